// Round 9
// baseline (37.071 us; speedup 1.0000x reference)
//
#include <hip/hip_runtime.h>
#include <stdint.h>

// ---------------------------------------------------------------------------
// JAX threefry2x32, PARTITIONABLE mode (verified bit-exact in R3):
//   split(key,n)[i]              = threefry2x32(key, (0, i))          (both words)
//   random_bits(key,32,shape)[i] = bits1 ^ bits2 of that block        (XOR-fold)
// ---------------------------------------------------------------------------

struct U2 { uint32_t x, y; };

typedef float f32x4 __attribute__((ext_vector_type(4)));

__device__ __forceinline__ uint32_t rotl32(uint32_t v, int r) {
    return (v << r) | (v >> (32 - r));
}

__device__ U2 threefry2x32(uint32_t k0, uint32_t k1, uint32_t c0, uint32_t c1) {
    uint32_t ks2 = k0 ^ k1 ^ 0x1BD11BDAu;
    uint32_t x0 = c0 + k0;
    uint32_t x1 = c1 + k1;
#define TF_RND(r) { x0 += x1; x1 = rotl32(x1, r); x1 ^= x0; }
    TF_RND(13) TF_RND(15) TF_RND(26) TF_RND(6)
    x0 += k1;  x1 += ks2 + 1u;
    TF_RND(17) TF_RND(29) TF_RND(16) TF_RND(24)
    x0 += ks2; x1 += k0 + 2u;
    TF_RND(13) TF_RND(15) TF_RND(26) TF_RND(6)
    x0 += k0;  x1 += k1 + 3u;
    TF_RND(17) TF_RND(29) TF_RND(16) TF_RND(24)
    x0 += k1;  x1 += ks2 + 4u;
    TF_RND(13) TF_RND(15) TF_RND(26) TF_RND(6)
    x0 += ks2; x1 += k0 + 5u;
#undef TF_RND
    U2 r; r.x = x0; r.y = x1; return r;
}

__device__ __forceinline__ U2 blk(U2 key, uint32_t i) {
    return threefry2x32(key.x, key.y, 0u, i);
}
__device__ __forceinline__ uint32_t rb32(U2 key, uint32_t i) {
    U2 b = blk(key, i);
    return b.x ^ b.y;
}
__device__ __forceinline__ float u01(uint32_t bits) {
    uint32_t fb = (bits >> 9) | 0x3f800000u;
    return __uint_as_float(fb) - 1.0f;
}

// ---------------------------------------------------------------------------
#define BATCH 32
#define NHEADS 16
#define SEQ 785
#define SIDE 28
#define NDROP 8                          // max(1, int(16*0.5))

#define VPT 16                           // float4 per thread
#define TPB 256                          // threads per block
#define TOK_PER_BLK 256                  // (TPB*VPT)/16 tokens per block
// nvec = 6,430,720 = 1570 * 4096 exactly; tokens = 401,920 = 1570 * 256 exactly.

// Single fused kernel: 16 loads in flight, wave0 shuffle-permutation,
// one token-mask per thread (RNG spread over all waves), NT stores.
__global__ void __launch_bounds__(TPB)
fused_dropout_kernel(const f32x4* __restrict__ v, f32x4* __restrict__ out) {
    __shared__ int   lds_hm[NHEADS];        // head -> drop slot j, or -1
    __shared__ float lds_m[TOK_PER_BLK];    // per-token multiplier

    const U2 base = {0u, 42u};              // jax.random.key(42) data = [0,42]

    const int base4 = blockIdx.x * (TPB * VPT) + threadIdx.x;

    // 1) issue all 16 independent loads up front; RNG hides under HBM latency
    f32x4 r[VPT];
    #pragma unroll
    for (int k = 0; k < VPT; ++k) r[k] = v[base4 + k * TPB];

    // 2) head permutation in wave 0 via shuffles (no barrier needed inside):
    //    permutation(k_perm,16) = 1 shuffle round; stable argsort rank
    if (threadIdx.x < 64) {
        U2 k_perm = blk(base, 0);           // split(base,2)[0]
        U2 subkey = blk(k_perm, 1);         // key,subkey = split(k_perm)
        uint32_t sk = rb32(subkey, threadIdx.x & 15u);
        int rank = 0;
        #pragma unroll
        for (int i = 0; i < NHEADS; ++i) {
            uint32_t ski = __shfl(sk, i, 64);
            if (ski < sk || (ski == sk && i < (int)(threadIdx.x & 15u))) ++rank;
        }
        if (threadIdx.x < NHEADS)
            lds_hm[threadIdx.x] = (rank < NDROP) ? rank : -1;
    }
    __syncthreads();

    // 3) one token mask per thread (all 4 waves share the RNG work)
    {
        int tok = blockIdx.x * TOK_PER_BLK + (int)threadIdx.x;
        uint32_t s  = (uint32_t)tok % SEQ;
        uint32_t bh = (uint32_t)tok / SEQ;
        uint32_t h  = bh & (NHEADS - 1);
        uint32_t b  = bh >> 4;
        float m = 1.0f;
        int j = lds_hm[h];
        if (j >= 0 && s >= 1) {             // s==0 is the special token
            uint32_t pos = s - 1;
            uint32_t rr = pos / SIDE;
            uint32_t c  = pos - rr * SIDE;
            uint32_t br = b * SIDE + rr;
            U2 k_masks = blk(base, 1);      // split(base,2)[1]
            U2 hk      = blk(k_masks, (uint32_t)j);
            U2 k_row   = blk(hk, 0);
            if (u01(rb32(k_row, br)) < 0.1f) {              // row selected
                U2 k_start = blk(hk, 1);
                U2 kh = blk(k_start, 0);
                U2 kl = blk(k_start, 1);
                uint32_t hi = rb32(kh, br);
                uint32_t lo = rb32(kl, br);
                uint32_t start = ((hi % 27u) * 22u + (lo % 27u)) % 27u;
                int off = (int)c - (int)start;
                if (off >= 0 && off < 2) {                  // inside band
                    U2 k_drop = blk(hk, 2);
                    if (u01(rb32(k_drop, 2u * br + (uint32_t)off)) < 0.8f)
                        m = 0.0f;
                }
            }
        }
        lds_m[threadIdx.x] = m;
    }
    __syncthreads();

    // 4) multiply + nontemporal store; lds_m read is a 16-lane broadcast
    #pragma unroll
    for (int k = 0; k < VPT; ++k) {
        float m = lds_m[(threadIdx.x >> 4) + 16 * k];
        r[k] *= m;
        __builtin_nontemporal_store(r[k], &out[base4 + k * TPB]);
    }
}

extern "C" void kernel_launch(void* const* d_in, const int* in_sizes, int n_in,
                              void* d_out, int out_size, void* d_ws, size_t ws_size,
                              hipStream_t stream) {
    const float* v = (const float*)d_in[0];
    float* out = (float*)d_out;

    int nvec = out_size / 4;                      // 6,430,720 float4
    int blocks = nvec / (TPB * VPT);              // 1570, exact
    fused_dropout_kernel<<<blocks, TPB, 0, stream>>>(
        (const f32x4*)v, (f32x4*)out);
}

// Round 10
// 36.669 us; speedup vs baseline: 1.0110x; 1.0110x over previous
//
#include <hip/hip_runtime.h>
#include <stdint.h>

// ---------------------------------------------------------------------------
// JAX threefry2x32, PARTITIONABLE mode (verified bit-exact in R3):
//   split(key,n)[i]              = threefry2x32(key, (0, i))          (both words)
//   random_bits(key,32,shape)[i] = bits1 ^ bits2 of that block        (XOR-fold)
// ---------------------------------------------------------------------------
// R9 post-mortem: VPT=16 cost VGPR 32->48, occupancy 33%, dur +4 us profiled.
// VPT=8 (this version, == R8) is the measured optimum: 36.56 us harness,
// 206 MB @ ~5.6 TB/s ~= 89% of the 6.29 TB/s D2D ceiling incl. launch.
// ---------------------------------------------------------------------------

struct U2 { uint32_t x, y; };

typedef float f32x4 __attribute__((ext_vector_type(4)));

__device__ __forceinline__ uint32_t rotl32(uint32_t v, int r) {
    return (v << r) | (v >> (32 - r));
}

__device__ U2 threefry2x32(uint32_t k0, uint32_t k1, uint32_t c0, uint32_t c1) {
    uint32_t ks2 = k0 ^ k1 ^ 0x1BD11BDAu;
    uint32_t x0 = c0 + k0;
    uint32_t x1 = c1 + k1;
#define TF_RND(r) { x0 += x1; x1 = rotl32(x1, r); x1 ^= x0; }
    TF_RND(13) TF_RND(15) TF_RND(26) TF_RND(6)
    x0 += k1;  x1 += ks2 + 1u;
    TF_RND(17) TF_RND(29) TF_RND(16) TF_RND(24)
    x0 += ks2; x1 += k0 + 2u;
    TF_RND(13) TF_RND(15) TF_RND(26) TF_RND(6)
    x0 += k0;  x1 += k1 + 3u;
    TF_RND(17) TF_RND(29) TF_RND(16) TF_RND(24)
    x0 += k1;  x1 += ks2 + 4u;
    TF_RND(13) TF_RND(15) TF_RND(26) TF_RND(6)
    x0 += ks2; x1 += k0 + 5u;
#undef TF_RND
    U2 r; r.x = x0; r.y = x1; return r;
}

__device__ __forceinline__ U2 blk(U2 key, uint32_t i) {
    return threefry2x32(key.x, key.y, 0u, i);
}
__device__ __forceinline__ uint32_t rb32(U2 key, uint32_t i) {
    U2 b = blk(key, i);
    return b.x ^ b.y;
}
__device__ __forceinline__ float u01(uint32_t bits) {
    uint32_t fb = (bits >> 9) | 0x3f800000u;
    return __uint_as_float(fb) - 1.0f;
}

// ---------------------------------------------------------------------------
#define BATCH 32
#define NHEADS 16
#define SEQ 785
#define SIDE 28
#define NDROP 8                          // max(1, int(16*0.5))

#define VPT 8                            // float4 per thread
#define TPB 256                          // threads per block
#define TOK_PER_BLK ((TPB * VPT) / 16)   // 128 tokens (64 floats each)
// nvec = 6,430,720 = 3140 * 2048 exactly -> every block full, no tail.

// Single fused kernel: copy + on-the-fly mask recompute + NT store.
// Loads issued first; RNG (LDS-staged, per-block) hides under HBM latency.
__global__ void __launch_bounds__(TPB)
fused_dropout_kernel(const f32x4* __restrict__ v, f32x4* __restrict__ out) {
    __shared__ uint32_t lds_sk[NHEADS];
    __shared__ int      lds_hm[NHEADS];      // head -> drop slot j, or -1
    __shared__ float    lds_m[TOK_PER_BLK];  // per-token multiplier

    const U2 base = {0u, 42u};               // jax.random.key(42) data = [0,42]

    const int base4 = blockIdx.x * (TPB * VPT) + threadIdx.x;

    // 1) issue all 8 independent loads up front (waitcnt lands after barrier)
    f32x4 r[VPT];
    #pragma unroll
    for (int k = 0; k < VPT; ++k) r[k] = v[base4 + k * TPB];

    // 2) head permutation: permutation(k_perm, 16), 1 shuffle round
    if (threadIdx.x < NHEADS) {
        U2 k_perm = blk(base, 0);            // split(base,2)[0]
        U2 subkey = blk(k_perm, 1);          // key,subkey = split(k_perm)
        lds_sk[threadIdx.x] = rb32(subkey, threadIdx.x);
    }
    __syncthreads();
    if (threadIdx.x < NHEADS) {
        uint32_t mysk = lds_sk[threadIdx.x];
        int rank = 0;
        for (int i = 0; i < NHEADS; ++i)
            if (lds_sk[i] < mysk || (lds_sk[i] == mysk && i < (int)threadIdx.x)) ++rank;
        lds_hm[threadIdx.x] = (rank < NDROP) ? rank : -1;   // head_idx slot
    }
    __syncthreads();

    // 3) per-token mask (threads 0..127), short-circuiting RNG chain
    if (threadIdx.x < TOK_PER_BLK) {
        int tok = blockIdx.x * TOK_PER_BLK + threadIdx.x;
        uint32_t s  = (uint32_t)tok % SEQ;
        uint32_t bh = (uint32_t)tok / SEQ;
        uint32_t h  = bh & (NHEADS - 1);
        uint32_t b  = bh >> 4;
        float m = 1.0f;
        int j = lds_hm[h];
        if (j >= 0 && s >= 1) {              // s==0 is the special token
            uint32_t pos = s - 1;
            uint32_t rr = pos / SIDE;
            uint32_t c  = pos - rr * SIDE;
            uint32_t br = b * SIDE + rr;
            U2 k_masks = blk(base, 1);       // split(base,2)[1]
            U2 hk      = blk(k_masks, (uint32_t)j);
            U2 k_row   = blk(hk, 0);
            if (u01(rb32(k_row, br)) < 0.1f) {               // row selected
                U2 k_start = blk(hk, 1);
                U2 kh = blk(k_start, 0);
                U2 kl = blk(k_start, 1);
                uint32_t hi = rb32(kh, br);
                uint32_t lo = rb32(kl, br);
                uint32_t start = ((hi % 27u) * 22u + (lo % 27u)) % 27u;
                int off = (int)c - (int)start;
                if (off >= 0 && off < 2) {                   // inside band
                    U2 k_drop = blk(hk, 2);
                    if (u01(rb32(k_drop, 2u * br + (uint32_t)off)) < 0.8f)
                        m = 0.0f;
                }
            }
        }
        lds_m[threadIdx.x] = m;
    }
    __syncthreads();

    // 4) multiply + nontemporal store
    #pragma unroll
    for (int k = 0; k < VPT; ++k) {
        int i4 = threadIdx.x + k * TPB;      // local float4 index in block span
        float m = lds_m[i4 >> 4];
        r[k] *= m;
        __builtin_nontemporal_store(r[k], &out[base4 + k * TPB]);
    }
}

extern "C" void kernel_launch(void* const* d_in, const int* in_sizes, int n_in,
                              void* d_out, int out_size, void* d_ws, size_t ws_size,
                              hipStream_t stream) {
    const float* v = (const float*)d_in[0];
    float* out = (float*)d_out;

    int nvec = out_size / 4;                      // 6,430,720 float4
    int blocks = nvec / (TPB * VPT);              // 3140, exact
    fused_dropout_kernel<<<blocks, TPB, 0, stream>>>(
        (const f32x4*)v, (f32x4*)out);
}